// Round 1
// baseline (1475.012 us; speedup 1.0000x reference)
//
#include <hip/hip_runtime.h>
#include <math.h>

#define NN 10000
#define EE 320000
#define DD 128
#define NHEAD 16
#define EFD 4
#define NGAUSS 20
#define KVD 340
#define EPSf 1e-5f

// ---------- order-preserving float<->uint encoding for atomicMax ----------
__device__ __forceinline__ unsigned enc_f32(float f) {
    unsigned u = __float_as_uint(f);
    return (u & 0x80000000u) ? ~u : (u | 0x80000000u);
}
__device__ __forceinline__ float dec_f32(unsigned u) {
    return (u & 0x80000000u) ? __uint_as_float(u & 0x7FFFFFFFu)
                             : __uint_as_float(~u);
}
#define ENC_NEG_INF 0x007FFFFFu   // enc(-inf)

// ---------------------- init: segmax/-inf, denom/0, out/0 ----------------------
__global__ void k_init(unsigned* __restrict__ segmax, float* __restrict__ denom,
                       float* __restrict__ out) {
    int i = blockIdx.x * 256 + threadIdx.x;
    if (i < NN * NHEAD) { segmax[i] = ENC_NEG_INF; denom[i] = 0.f; }
    if (i < NN * 3) out[i] = 0.f;
}

// ---------------------- q = MLP(h): 128 -> 128 -> LN -> ReLU -> 128 ----------------------
__global__ __launch_bounds__(256) void k_qmlp(
    const float* __restrict__ h,
    const float* __restrict__ W1, const float* __restrict__ b1,
    const float* __restrict__ g,  const float* __restrict__ bt,
    const float* __restrict__ W2, const float* __restrict__ b2,
    float* __restrict__ q)
{
    __shared__ float sH[32 * 128];
    __shared__ float sY[32 * 128];
    const int tid = threadIdx.x;
    const int n0 = blockIdx.x * 32;

    // load 32-node h tile (clamped)
    #pragma unroll
    for (int j = 0; j < 4; ++j) {
        int p = tid + j * 256;          // [0,1024)
        int e = p >> 5, i = p & 31;
        int node = n0 + e; if (node >= NN) node = NN - 1;
        float4 v = *(const float4*)(h + node * 128 + i * 4);
        *(float4*)(sH + e * 128 + i * 4) = v;
    }
    __syncthreads();

    const int c  = tid & 127;
    const int eg = (tid >> 7) * 16;
    float acc[16];
    #pragma unroll
    for (int e = 0; e < 16; ++e) acc[e] = 0.f;
    for (int k = 0; k < 128; k += 4) {
        float w0 = W1[(k + 0) * 128 + c], w1 = W1[(k + 1) * 128 + c];
        float w2 = W1[(k + 2) * 128 + c], w3 = W1[(k + 3) * 128 + c];
        #pragma unroll
        for (int e = 0; e < 16; ++e) {
            float4 a = *(const float4*)(sH + (eg + e) * 128 + k);
            acc[e] += a.x * w0 + a.y * w1 + a.z * w2 + a.w * w3;
        }
    }
    {
        float bb = b1[c];
        #pragma unroll
        for (int e = 0; e < 16; ++e) sY[(eg + e) * 128 + c] = acc[e] + bb;
    }
    __syncthreads();

    // LayerNorm + ReLU: 32 rows, 8 lanes per row
    {
        int r = tid >> 3, s = tid & 7;
        float* row = sY + r * 128;
        float vals[16];
        float sum = 0.f, sq = 0.f;
        #pragma unroll
        for (int j = 0; j < 4; ++j) {
            float4 v = *(float4*)(row + s * 16 + j * 4);
            vals[j*4+0] = v.x; vals[j*4+1] = v.y; vals[j*4+2] = v.z; vals[j*4+3] = v.w;
        }
        #pragma unroll
        for (int j = 0; j < 16; ++j) { sum += vals[j]; sq += vals[j] * vals[j]; }
        #pragma unroll
        for (int o = 1; o < 8; o <<= 1) { sum += __shfl_xor(sum, o, 64); sq += __shfl_xor(sq, o, 64); }
        float mu = sum * (1.f / 128.f);
        float var = sq * (1.f / 128.f) - mu * mu;
        float rs = rsqrtf(var + EPSf);
        #pragma unroll
        for (int j = 0; j < 16; ++j) {
            int col = s * 16 + j;
            float a = (vals[j] - mu) * rs * g[col] + bt[col];
            row[col] = a > 0.f ? a : 0.f;
        }
    }
    __syncthreads();

    #pragma unroll
    for (int e = 0; e < 16; ++e) acc[e] = 0.f;
    for (int k = 0; k < 128; k += 4) {
        float w0 = W2[(k + 0) * 128 + c], w1 = W2[(k + 1) * 128 + c];
        float w2 = W2[(k + 2) * 128 + c], w3 = W2[(k + 3) * 128 + c];
        #pragma unroll
        for (int e = 0; e < 16; ++e) {
            float4 a = *(const float4*)(sY + (eg + e) * 128 + k);
            acc[e] += a.x * w0 + a.y * w1 + a.z * w2 + a.w * w3;
        }
    }
    {
        float bb = b2[c];
        #pragma unroll
        for (int e = 0; e < 16; ++e) {
            int node = n0 + eg + e;
            if (node < NN) q[node * 128 + c] = acc[e] + bb;
        }
    }
}

// ------- per-edge: build kv, fused k/v MLP layer1, LN, layer2, logits -------
__global__ __launch_bounds__(256) void k_edge(
    const float* __restrict__ x,  const float* __restrict__ h,
    const float* __restrict__ ea, const int* __restrict__ ei,
    const float* __restrict__ kW1, const float* __restrict__ kb1,
    const float* __restrict__ kg,  const float* __restrict__ kbt,
    const float* __restrict__ kW2, const float* __restrict__ kb2,
    const float* __restrict__ vW1, const float* __restrict__ vb1,
    const float* __restrict__ vg,  const float* __restrict__ vbt,
    const float* __restrict__ vW2, const float* __restrict__ vb2,
    const float* __restrict__ q,
    float* __restrict__ logits, float* __restrict__ vout,
    float* __restrict__ relx)
{
    __shared__ float sA[32 * 340];   // kv tile; reused later as k_out[32][128]
    __shared__ float sY[64 * 128];   // y/activations, row = e*2 + half (0=k,1=v)
    __shared__ float sDist[32];
    __shared__ int   sSrc[32], sDst[32];

    const int tid = threadIdx.x;
    const int e0  = blockIdx.x * 32;

    if (tid < 32) {
        int e = e0 + tid;
        int s = ei[e], d = ei[EE + e];
        sSrc[tid] = s; sDst[tid] = d;
        float rx = x[d * 3 + 0] - x[s * 3 + 0];
        float ry = x[d * 3 + 1] - x[s * 3 + 1];
        float rz = x[d * 3 + 2] - x[s * 3 + 2];
        relx[e * 3 + 0] = rx; relx[e * 3 + 1] = ry; relx[e * 3 + 2] = rz;
        sDist[tid] = sqrtf(rx * rx + ry * ry + rz * rz);
        sA[tid * 340 + 0] = ea[e * 4 + 0];
        sA[tid * 340 + 1] = ea[e * 4 + 1];
        sA[tid * 340 + 2] = ea[e * 4 + 2];
        sA[tid * 340 + 3] = ea[e * 4 + 3];
    }
    __syncthreads();

    // dist_feat: kv[4 + f*20 + g] = edge_attr[f] * exp(coeff*(dist - off_g)^2)
    const float step  = 10.0f / 19.0f;
    const float coeff = -0.5f / (step * step);
    #pragma unroll
    for (int j = 0; j < 10; ++j) {
        int p = tid + j * 256;          // [0, 2560)
        int e = p / 80, i = p % 80;
        int f = i / 20, gi = i % 20;
        float dd = sDist[e] - (float)gi * step;
        sA[e * 340 + 4 + i] = sA[e * 340 + f] * __expf(coeff * dd * dd);
    }
    // h gather: kv[84..211] = h[dst], kv[212..339] = h[src]
    #pragma unroll
    for (int j = 0; j < 8; ++j) {
        int p = tid + j * 256;          // [0, 2048)
        int e = p >> 6, r = p & 63;
        int half = r >> 5, i = r & 31;
        int node = half ? sSrc[e] : sDst[e];
        float4 v = *(const float4*)(h + node * 128 + i * 4);
        *(float4*)(sA + e * 340 + 84 + half * 128 + i * 4) = v;
    }
    __syncthreads();

    const int c  = tid & 127;
    const int eg = (tid >> 7) * 16;

    // layer 1: [32,340] @ [340, 128+128]
    float acck[16], accv[16];
    #pragma unroll
    for (int e = 0; e < 16; ++e) { acck[e] = 0.f; accv[e] = 0.f; }
    for (int k = 0; k < 340; k += 4) {
        float kw0 = kW1[(k + 0) * 128 + c], kw1 = kW1[(k + 1) * 128 + c];
        float kw2 = kW1[(k + 2) * 128 + c], kw3 = kW1[(k + 3) * 128 + c];
        float vw0 = vW1[(k + 0) * 128 + c], vw1 = vW1[(k + 1) * 128 + c];
        float vw2 = vW1[(k + 2) * 128 + c], vw3 = vW1[(k + 3) * 128 + c];
        #pragma unroll
        for (int e = 0; e < 16; ++e) {
            float4 a = *(const float4*)(sA + (eg + e) * 340 + k);
            acck[e] += a.x * kw0 + a.y * kw1 + a.z * kw2 + a.w * kw3;
            accv[e] += a.x * vw0 + a.y * vw1 + a.z * vw2 + a.w * vw3;
        }
    }
    {
        float bk = kb1[c], bv = vb1[c];
        #pragma unroll
        for (int e = 0; e < 16; ++e) {
            sY[((eg + e) * 2 + 0) * 128 + c] = acck[e] + bk;
            sY[((eg + e) * 2 + 1) * 128 + c] = accv[e] + bv;
        }
    }
    __syncthreads();

    // LayerNorm + ReLU: 64 rows (edge x {k,v}), 4 lanes per row
    {
        int r = tid >> 2, s = tid & 3;
        float* row = sY + r * 128;
        float vals[32];
        float sum = 0.f, sq = 0.f;
        #pragma unroll
        for (int j = 0; j < 8; ++j) {
            float4 v = *(float4*)(row + s * 32 + j * 4);
            vals[j*4+0] = v.x; vals[j*4+1] = v.y; vals[j*4+2] = v.z; vals[j*4+3] = v.w;
        }
        #pragma unroll
        for (int j = 0; j < 32; ++j) { sum += vals[j]; sq += vals[j] * vals[j]; }
        sum += __shfl_xor(sum, 1, 64); sq += __shfl_xor(sq, 1, 64);
        sum += __shfl_xor(sum, 2, 64); sq += __shfl_xor(sq, 2, 64);
        float mu = sum * (1.f / 128.f);
        float var = sq * (1.f / 128.f) - mu * mu;
        float rs = rsqrtf(var + EPSf);
        int half = r & 1;
        const float* gp = half ? vg : kg;
        const float* bp = half ? vbt : kbt;
        #pragma unroll
        for (int j = 0; j < 32; ++j) {
            int col = s * 32 + j;
            float a = (vals[j] - mu) * rs * gp[col] + bp[col];
            row[col] = a > 0.f ? a : 0.f;
        }
    }
    __syncthreads();

    // layer 2 (k): [32,128] @ [128,128] -> k_out into sA
    {
        float acc2[16];
        #pragma unroll
        for (int e = 0; e < 16; ++e) acc2[e] = 0.f;
        for (int k = 0; k < 128; k += 4) {
            float w0 = kW2[(k + 0) * 128 + c], w1 = kW2[(k + 1) * 128 + c];
            float w2 = kW2[(k + 2) * 128 + c], w3 = kW2[(k + 3) * 128 + c];
            #pragma unroll
            for (int e = 0; e < 16; ++e) {
                float4 a = *(const float4*)(sY + ((eg + e) * 2 + 0) * 128 + k);
                acc2[e] += a.x * w0 + a.y * w1 + a.z * w2 + a.w * w3;
            }
        }
        float bb = kb2[c];
        #pragma unroll
        for (int e = 0; e < 16; ++e) sA[(eg + e) * 128 + c] = acc2[e] + bb;
    }
    // layer 2 (v): [32,128] @ [128,16] -> vout global
    {
        int jj = tid & 15;
        int g2 = tid >> 4;              // 0..15 -> 2 edges each
        int ea0 = g2 * 2, ea1 = g2 * 2 + 1;
        float a0 = 0.f, a1 = 0.f;
        for (int k = 0; k < 128; k += 4) {
            float w0 = vW2[(k + 0) * 16 + jj], w1 = vW2[(k + 1) * 16 + jj];
            float w2 = vW2[(k + 2) * 16 + jj], w3 = vW2[(k + 3) * 16 + jj];
            float4 x0 = *(const float4*)(sY + (ea0 * 2 + 1) * 128 + k);
            float4 x1 = *(const float4*)(sY + (ea1 * 2 + 1) * 128 + k);
            a0 += x0.x * w0 + x0.y * w1 + x0.z * w2 + x0.w * w3;
            a1 += x1.x * w0 + x1.y * w1 + x1.z * w2 + x1.w * w3;
        }
        float bb = vb2[jj];
        vout[(e0 + ea0) * 16 + jj] = a0 + bb;
        vout[(e0 + ea1) * 16 + jj] = a1 + bb;
    }
    __syncthreads();

    // logits[e][h] = dot8(q[dst], k_out) / sqrt(8)
    #pragma unroll
    for (int j = 0; j < 2; ++j) {
        int p = tid + j * 256;          // [0,512)
        int e = p >> 4, hh = p & 15;
        const float* qn = q + sDst[e] * 128 + hh * 8;
        float4 q0 = *(const float4*)(qn);
        float4 q1 = *(const float4*)(qn + 4);
        float4 k0 = *(const float4*)(sA + e * 128 + hh * 8);
        float4 k1 = *(const float4*)(sA + e * 128 + hh * 8 + 4);
        float dot = q0.x * k0.x + q0.y * k0.y + q0.z * k0.z + q0.w * k0.w
                  + q1.x * k1.x + q1.y * k1.y + q1.z * k1.z + q1.w * k1.w;
        logits[(e0 + e) * 16 + hh] = dot * 0.35355339059327373f;
    }
}

// ---------------------- scatter softmax: pass 1 (max) ----------------------
__global__ void k_segmax(const int* __restrict__ ei, const float* __restrict__ logits,
                         unsigned* __restrict__ segmax) {
    int gid = blockIdx.x * 256 + threadIdx.x;   // E*16
    int e = gid >> 4, hh = gid & 15;
    int d = ei[EE + e];
    atomicMax(&segmax[d * 16 + hh], enc_f32(logits[gid]));
}

// ---------------------- pass 2: exp + denom ----------------------
__global__ void k_exp(const int* __restrict__ ei, float* __restrict__ logits,
                      const unsigned* __restrict__ segmax, float* __restrict__ denom) {
    int gid = blockIdx.x * 256 + threadIdx.x;   // E*16
    int e = gid >> 4, hh = gid & 15;
    int d = ei[EE + e];
    float m = dec_f32(segmax[d * 16 + hh]);
    float ex = __expf(logits[gid] - m);
    logits[gid] = ex;                            // overwrite with exp
    atomicAdd(&denom[d * 16 + hh], ex);
}

// ---------------------- pass 3: alpha * v * rel_x, scatter to out ----------------------
__global__ void k_scatter(const int* __restrict__ ei, const float* __restrict__ exs,
                          const float* __restrict__ denom, const float* __restrict__ vout,
                          const float* __restrict__ relx, float* __restrict__ out) {
    int e = blockIdx.x * 256 + threadIdx.x;     // E
    int d = ei[EE + e];
    const float* ex = exs + e * 16;
    const float* dn = denom + d * 16;
    const float* vv = vout + e * 16;
    float s = 0.f;
    #pragma unroll
    for (int hh = 0; hh < 16; ++hh) s += ex[hh] / dn[hh] * vv[hh];
    s *= (1.0f / 16.0f);
    atomicAdd(&out[d * 3 + 0], s * relx[e * 3 + 0]);
    atomicAdd(&out[d * 3 + 1], s * relx[e * 3 + 1]);
    atomicAdd(&out[d * 3 + 2], s * relx[e * 3 + 2]);
}

extern "C" void kernel_launch(void* const* d_in, const int* in_sizes, int n_in,
                              void* d_out, int out_size, void* d_ws, size_t ws_size,
                              hipStream_t stream) {
    const float* x   = (const float*)d_in[0];
    const float* h   = (const float*)d_in[1];
    const float* ea  = (const float*)d_in[2];
    // d_in[3] = e_w (unused: ew_net_type 'm')
    const int*   ei  = (const int*)d_in[4];
    const float* kW1 = (const float*)d_in[5];
    const float* kb1 = (const float*)d_in[6];
    const float* kg  = (const float*)d_in[7];
    const float* kbt = (const float*)d_in[8];
    const float* kW2 = (const float*)d_in[9];
    const float* kb2 = (const float*)d_in[10];
    const float* vW1 = (const float*)d_in[11];
    const float* vb1 = (const float*)d_in[12];
    const float* vg  = (const float*)d_in[13];
    const float* vbt = (const float*)d_in[14];
    const float* vW2 = (const float*)d_in[15];
    const float* vb2 = (const float*)d_in[16];
    const float* qW1 = (const float*)d_in[17];
    const float* qb1 = (const float*)d_in[18];
    const float* qg  = (const float*)d_in[19];
    const float* qbt = (const float*)d_in[20];
    const float* qW2 = (const float*)d_in[21];
    const float* qb2 = (const float*)d_in[22];

    float* ws = (float*)d_ws;
    float*    qbuf   = ws;                         // N*128   = 1,280,000
    float*    logits = ws + 1280000;               // E*16    = 5,120,000
    float*    vbuf   = ws + 6400000;               // E*16    = 5,120,000
    float*    relx   = ws + 11520000;              // E*3     =   960,000
    unsigned* segmax = (unsigned*)(ws + 12480000); // N*16    =   160,000
    float*    denom  = ws + 12640000;              // N*16    =   160,000
    float*    out    = (float*)d_out;

    hipLaunchKernelGGL(k_init, dim3(625), dim3(256), 0, stream, segmax, denom, out);
    hipLaunchKernelGGL(k_qmlp, dim3(313), dim3(256), 0, stream,
                       h, qW1, qb1, qg, qbt, qW2, qb2, qbuf);
    hipLaunchKernelGGL(k_edge, dim3(10000), dim3(256), 0, stream,
                       x, h, ea, ei,
                       kW1, kb1, kg, kbt, kW2, kb2,
                       vW1, vb1, vg, vbt, vW2, vb2,
                       qbuf, logits, vbuf, relx);
    hipLaunchKernelGGL(k_segmax, dim3(20000), dim3(256), 0, stream, ei, logits, segmax);
    hipLaunchKernelGGL(k_exp, dim3(20000), dim3(256), 0, stream, ei, logits, segmax, denom);
    hipLaunchKernelGGL(k_scatter, dim3(1250), dim3(256), 0, stream,
                       ei, logits, denom, vbuf, relx, out);
}

// Round 2
// 306.954 us; speedup vs baseline: 4.8053x; 4.8053x over previous
//
#include <hip/hip_runtime.h>
#include <math.h>

typedef __attribute__((ext_vector_type(8))) short short8;
typedef __attribute__((ext_vector_type(4))) float f32x4;

#define NN 10000
#define EE 320000
#define NHEAD 16
#define EPSf 1e-5f

// ---------- bf16 helpers ----------
__device__ __forceinline__ unsigned short f2bf(float f) {
    union { float f; unsigned u; } v; v.f = f;
    unsigned u = v.u;
    u += 0x7fffu + ((u >> 16) & 1u);   // RNE
    return (unsigned short)(u >> 16);
}
__device__ __forceinline__ float bf2f(unsigned short s) {
    union { unsigned u; float f; } v; v.u = ((unsigned)s) << 16;
    return v.f;
}

// ---------- order-preserving float<->uint encoding for atomicMax ----------
__device__ __forceinline__ unsigned enc_f32(float f) {
    unsigned u = __float_as_uint(f);
    return (u & 0x80000000u) ? ~u : (u | 0x80000000u);
}
__device__ __forceinline__ float dec_f32(unsigned u) {
    return (u & 0x80000000u) ? __uint_as_float(u & 0x7FFFFFFFu)
                             : __uint_as_float(~u);
}
#define ENC_NEG_INF 0x007FFFFFu

// ---------------------- init ----------------------
__global__ void k_init(unsigned* __restrict__ segmax, float* __restrict__ denom,
                       float* __restrict__ out) {
    int i = blockIdx.x * 256 + threadIdx.x;
    if (i < NN * NHEAD) { segmax[i] = ENC_NEG_INF; denom[i] = 0.f; }
    if (i < NN * 3) out[i] = 0.f;
}

// ------------- prep: bf16-convert h; transpose+bf16+K-permute weights -------------
// kv layout (k'): [0..127]=h_dst, [128..255]=h_src, [256..259]=ea, [260..339]=dist, [340..383]=0
__global__ void k_prep(const float* __restrict__ h,
                       const float* __restrict__ kW1, const float* __restrict__ vW1,
                       const float* __restrict__ kW2, const float* __restrict__ vW2,
                       unsigned short* __restrict__ h_bf, unsigned short* __restrict__ Wt1,
                       unsigned short* __restrict__ kW2t, unsigned short* __restrict__ vW2t) {
    int i = blockIdx.x * 256 + threadIdx.x;
    if (i < NN * 128) { h_bf[i] = f2bf(h[i]); return; }
    int j = i - NN * 128;
    if (j < 256 * 352) {
        int n = j / 352, k = j % 352;
        float val = 0.f;
        if (k < 340) {
            int pk;
            if (k < 128)      pk = 84 + k;
            else if (k < 256) pk = 212 + (k - 128);
            else if (k < 260) pk = k - 256;
            else              pk = 4 + (k - 260);
            val = (n < 128) ? kW1[pk * 128 + n] : vW1[pk * 128 + (n - 128)];
        }
        Wt1[j] = f2bf(val); return;
    }
    j -= 256 * 352;
    if (j < 128 * 128) { int n = j >> 7, k = j & 127; kW2t[j] = f2bf(kW2[k * 128 + n]); return; }
    j -= 128 * 128;
    if (j < 16 * 128)  { int n = j >> 7, k = j & 127; vW2t[j] = f2bf(vW2[k * 16 + n]); return; }
}

// ---------------------- q = MLP(h) in f32 (small) ----------------------
__global__ __launch_bounds__(256) void k_qmlp(
    const float* __restrict__ h,
    const float* __restrict__ W1, const float* __restrict__ b1,
    const float* __restrict__ g,  const float* __restrict__ bt,
    const float* __restrict__ W2, const float* __restrict__ b2,
    float* __restrict__ q)
{
    __shared__ float sH[32 * 128];
    __shared__ float sY[32 * 128];
    const int tid = threadIdx.x;
    const int n0 = blockIdx.x * 32;

    #pragma unroll
    for (int j = 0; j < 4; ++j) {
        int p = tid + j * 256;
        int e = p >> 5, i = p & 31;
        int node = n0 + e; if (node >= NN) node = NN - 1;
        float4 v = *(const float4*)(h + node * 128 + i * 4);
        *(float4*)(sH + e * 128 + i * 4) = v;
    }
    __syncthreads();

    const int c  = tid & 127;
    const int eg = (tid >> 7) * 16;
    float acc[16];
    #pragma unroll
    for (int e = 0; e < 16; ++e) acc[e] = 0.f;
    for (int k = 0; k < 128; k += 4) {
        float w0 = W1[(k + 0) * 128 + c], w1 = W1[(k + 1) * 128 + c];
        float w2 = W1[(k + 2) * 128 + c], w3 = W1[(k + 3) * 128 + c];
        #pragma unroll
        for (int e = 0; e < 16; ++e) {
            float4 a = *(const float4*)(sH + (eg + e) * 128 + k);
            acc[e] += a.x * w0 + a.y * w1 + a.z * w2 + a.w * w3;
        }
    }
    {
        float bb = b1[c];
        #pragma unroll
        for (int e = 0; e < 16; ++e) sY[(eg + e) * 128 + c] = acc[e] + bb;
    }
    __syncthreads();

    {
        int r = tid >> 3, s = tid & 7;
        float* row = sY + r * 128;
        float vals[16];
        float sum = 0.f, sq = 0.f;
        #pragma unroll
        for (int j = 0; j < 4; ++j) {
            float4 v = *(float4*)(row + s * 16 + j * 4);
            vals[j*4+0] = v.x; vals[j*4+1] = v.y; vals[j*4+2] = v.z; vals[j*4+3] = v.w;
        }
        #pragma unroll
        for (int j = 0; j < 16; ++j) { sum += vals[j]; sq += vals[j] * vals[j]; }
        #pragma unroll
        for (int o = 1; o < 8; o <<= 1) { sum += __shfl_xor(sum, o, 64); sq += __shfl_xor(sq, o, 64); }
        float mu = sum * (1.f / 128.f);
        float var = sq * (1.f / 128.f) - mu * mu;
        float rs = rsqrtf(var + EPSf);
        #pragma unroll
        for (int j = 0; j < 16; ++j) {
            int col = s * 16 + j;
            float a = (vals[j] - mu) * rs * g[col] + bt[col];
            row[col] = a > 0.f ? a : 0.f;
        }
    }
    __syncthreads();

    #pragma unroll
    for (int e = 0; e < 16; ++e) acc[e] = 0.f;
    for (int k = 0; k < 128; k += 4) {
        float w0 = W2[(k + 0) * 128 + c], w1 = W2[(k + 1) * 128 + c];
        float w2 = W2[(k + 2) * 128 + c], w3 = W2[(k + 3) * 128 + c];
        #pragma unroll
        for (int e = 0; e < 16; ++e) {
            float4 a = *(const float4*)(sY + (eg + e) * 128 + k);
            acc[e] += a.x * w0 + a.y * w1 + a.z * w2 + a.w * w3;
        }
    }
    {
        float bb = b2[c];
        #pragma unroll
        for (int e = 0; e < 16; ++e) {
            int node = n0 + eg + e;
            if (node < NN) q[node * 128 + c] = acc[e] + bb;
        }
    }
}

// ------- per-edge MFMA kernel: build kv(bf16,swizzled), L1, LN, L2k, L2v, logits -------
__global__ __launch_bounds__(256, 3) void k_edge(
    const float* __restrict__ x, const unsigned short* __restrict__ h_bf,
    const float* __restrict__ ea, const int* __restrict__ ei,
    const unsigned short* __restrict__ Wt1,
    const float* __restrict__ kb1, const float* __restrict__ vb1,
    const float* __restrict__ kg, const float* __restrict__ kbt,
    const float* __restrict__ vg, const float* __restrict__ vbt,
    const unsigned short* __restrict__ kW2t, const float* __restrict__ kb2,
    const unsigned short* __restrict__ vW2t, const float* __restrict__ vb2,
    const float* __restrict__ q,
    float* __restrict__ logits, float* __restrict__ vout, float* __restrict__ relx)
{
    // region: phase A = kv tile [64 rows][384 halves] (48 chunks/row, xor-swizzled)
    // later:  Y [64][256 halves] at 0 (32 chunks/row) + k_out [64][128 halves] at 16384 (16 chunks/row)
    __shared__ __align__(16) unsigned short sR[64 * 384];
    __shared__ float sGB[512];     // kg,kbt,vg,vbt
    __shared__ float sEA[64 * 4];
    __shared__ float sDist[64];
    __shared__ int   sSrc[64], sDst[64];

    const int tid  = threadIdx.x;
    const int e0   = blockIdx.x * 64;
    const int lane = tid & 63;
    const int wv   = tid >> 6;
    const int rA   = lane & 15;
    const int kq   = lane >> 4;

    sGB[tid]       = (tid < 128) ? kg[tid] : kbt[tid - 128];
    sGB[tid + 256] = (tid < 128) ? vg[tid] : vbt[tid - 128];

    if (tid < 64) {
        int e = e0 + tid;
        int s = ei[e], d = ei[EE + e];
        sSrc[tid] = s; sDst[tid] = d;
        float rx = x[d*3+0] - x[s*3+0];
        float ry = x[d*3+1] - x[s*3+1];
        float rz = x[d*3+2] - x[s*3+2];
        relx[e*3+0] = rx; relx[e*3+1] = ry; relx[e*3+2] = rz;
        sDist[tid] = sqrtf(rx*rx + ry*ry + rz*rz);
        sEA[tid*4+0] = ea[e*4+0]; sEA[tid*4+1] = ea[e*4+1];
        sEA[tid*4+2] = ea[e*4+2]; sEA[tid*4+3] = ea[e*4+3];
    }
    __syncthreads();

    // h gather: rows x chunks 0..31 (k' 0..255); chunk<16 -> h[dst], else h[src]
    #pragma unroll
    for (int it = 0; it < 8; ++it) {
        int p = tid + it * 256;          // 0..2047
        int r = p >> 5, c = p & 31;
        int node = (c < 16) ? sDst[r] : sSrc[r];
        int cc = c & 15;
        uint4 v = *(const uint4*)(h_bf + node * 128 + cc * 8);
        *(uint4*)(&sR[r * 384 + ((c ^ (r & 7)) << 3)]) = v;
    }
    // ea + dist_feat + zero pad: k' 256..383
    const float step  = 10.0f / 19.0f;
    const float coeff = -0.5f / (step * step);
    #pragma unroll
    for (int it = 0; it < 32; ++it) {
        int p = tid + it * 256;          // 0..8191
        int r = p >> 7, i = p & 127;
        int k = 256 + i;
        float val;
        if (i < 4) val = sEA[r*4 + i];
        else if (i < 84) {
            int f = (i - 4) / 20, gg = (i - 4) % 20;
            float dd = sDist[r] - (float)gg * step;
            val = sEA[r*4 + f] * __expf(coeff * dd * dd);
        } else val = 0.f;
        int c = k >> 3;
        sR[r * 384 + ((c ^ (r & 7)) << 3) + (k & 7)] = f2bf(val);
    }
    __syncthreads();

    // ---- layer 1: [64,352]x[352,256], wave wv owns cols n0..n0+63 ----
    const int n0 = wv * 64;
    f32x4 zf = {0.f, 0.f, 0.f, 0.f};
    f32x4 acc[4][4];
    #pragma unroll
    for (int mf = 0; mf < 4; ++mf)
        #pragma unroll
        for (int nf = 0; nf < 4; ++nf) acc[mf][nf] = zf;

    for (int k0 = 0; k0 < 352; k0 += 32) {
        int cbase = (k0 >> 3) + kq;
        short8 a[4], b[4];
        #pragma unroll
        for (int mf = 0; mf < 4; ++mf) {
            int r = mf * 16 + rA;
            a[mf] = *(const short8*)(&sR[r * 384 + ((cbase ^ (r & 7)) << 3)]);
        }
        #pragma unroll
        for (int nf = 0; nf < 4; ++nf) {
            int n = n0 + nf * 16 + rA;
            b[nf] = *(const short8*)(Wt1 + n * 352 + k0 + kq * 8);
        }
        #pragma unroll
        for (int mf = 0; mf < 4; ++mf)
            #pragma unroll
            for (int nf = 0; nf < 4; ++nf)
                acc[mf][nf] = __builtin_amdgcn_mfma_f32_16x16x32_bf16(a[mf], b[nf], acc[mf][nf], 0, 0, 0);
    }
    __syncthreads();   // everyone done reading kv region

    // ---- write Y = acc + b1 as bf16 (swizzled, 32 chunks/row) ----
    {
        float bb[4];
        #pragma unroll
        for (int nf = 0; nf < 4; ++nf) {
            int col = n0 + nf * 16 + rA;
            bb[nf] = (col < 128) ? kb1[col] : vb1[col - 128];
        }
        #pragma unroll
        for (int mf = 0; mf < 4; ++mf)
            #pragma unroll
            for (int nf = 0; nf < 4; ++nf) {
                int col = n0 + nf * 16 + rA;
                int c = col >> 3, w = col & 7;
                #pragma unroll
                for (int j = 0; j < 4; ++j) {
                    int r = mf * 16 + kq * 4 + j;
                    sR[r * 256 + ((c ^ (r & 7)) << 3) + w] = f2bf(acc[mf][nf][j] + bb[nf]);
                }
            }
    }
    __syncthreads();

    // ---- LayerNorm + ReLU in place: 128 LN-rows (64 edges x {k,v}), 2 threads/row ----
    {
        int lr = tid >> 1;              // 0..127
        int e  = lr >> 1, half = lr & 1, sub = tid & 1;
        int cb = half * 16 + sub * 8;
        float sum = 0.f, sq = 0.f;
        #pragma unroll
        for (int i = 0; i < 8; ++i) {
            int c = cb + i;
            short8 vv = *(const short8*)(&sR[e * 256 + ((c ^ (e & 7)) << 3)]);
            #pragma unroll
            for (int j = 0; j < 8; ++j) {
                float f = bf2f((unsigned short)vv[j]);
                sum += f; sq += f * f;
            }
        }
        sum += __shfl_xor(sum, 1, 64); sq += __shfl_xor(sq, 1, 64);
        float mu  = sum * (1.f / 128.f);
        float var = sq  * (1.f / 128.f) - mu * mu;
        float rs  = rsqrtf(var + EPSf);
        const float* gp = sGB + half * 256;
        const float* bp = sGB + half * 256 + 128;
        #pragma unroll
        for (int i = 0; i < 8; ++i) {
            int c = cb + i;
            int off = e * 256 + ((c ^ (e & 7)) << 3);
            short8 vv = *(const short8*)(&sR[off]);
            short8 ov;
            #pragma unroll
            for (int j = 0; j < 8; ++j) {
                int col = sub * 64 + i * 8 + j;
                float f = bf2f((unsigned short)vv[j]);
                f = (f - mu) * rs * gp[col] + bp[col];
                f = f > 0.f ? f : 0.f;
                ov[j] = (short)f2bf(f);
            }
            *(short8*)(&sR[off]) = ov;
        }
    }
    __syncthreads();

    // ---- layer 2 (k): Y[:,0:128] x kW2t -> k_out (LDS at 16384, 16 chunks/row) ----
    {
        const int n0k = wv * 32;
        f32x4 a2[4][2];
        #pragma unroll
        for (int mf = 0; mf < 4; ++mf) { a2[mf][0] = zf; a2[mf][1] = zf; }
        for (int k0 = 0; k0 < 128; k0 += 32) {
            int cbase = (k0 >> 3) + kq;
            short8 a[4], b[2];
            #pragma unroll
            for (int mf = 0; mf < 4; ++mf) {
                int r = mf * 16 + rA;
                a[mf] = *(const short8*)(&sR[r * 256 + ((cbase ^ (r & 7)) << 3)]);
            }
            #pragma unroll
            for (int nf = 0; nf < 2; ++nf) {
                int n = n0k + nf * 16 + rA;
                b[nf] = *(const short8*)(kW2t + n * 128 + k0 + kq * 8);
            }
            #pragma unroll
            for (int mf = 0; mf < 4; ++mf)
                #pragma unroll
                for (int nf = 0; nf < 2; ++nf)
                    a2[mf][nf] = __builtin_amdgcn_mfma_f32_16x16x32_bf16(a[mf], b[nf], a2[mf][nf], 0, 0, 0);
        }
        #pragma unroll
        for (int mf = 0; mf < 4; ++mf)
            #pragma unroll
            for (int nf = 0; nf < 2; ++nf) {
                int col = n0k + nf * 16 + rA;
                int c = col >> 3, w = col & 7;
                float bb = kb2[col];
                #pragma unroll
                for (int j = 0; j < 4; ++j) {
                    int r = mf * 16 + kq * 4 + j;
                    sR[16384 + r * 128 + ((c ^ (r & 7)) << 3) + w] = f2bf(a2[mf][nf][j] + bb);
                }
            }
    }
    // ---- layer 2 (v): Y[:,128:256] x vW2t -> vout global; wave wv owns rows wv*16.. ----
    {
        f32x4 av = zf;
        for (int k0 = 0; k0 < 128; k0 += 32) {
            int cbase = 16 + (k0 >> 3) + kq;
            int r = wv * 16 + rA;
            short8 a = *(const short8*)(&sR[r * 256 + ((cbase ^ (r & 7)) << 3)]);
            short8 b = *(const short8*)(vW2t + rA * 128 + k0 + kq * 8);
            av = __builtin_amdgcn_mfma_f32_16x16x32_bf16(a, b, av, 0, 0, 0);
        }
        float bb = vb2[rA];
        #pragma unroll
        for (int j = 0; j < 4; ++j) {
            int r = wv * 16 + kq * 4 + j;
            vout[(e0 + r) * 16 + rA] = av[j] + bb;
        }
    }
    __syncthreads();

    // ---- logits[e][h] = dot8(q[dst], k_out)/sqrt(8) ----
    #pragma unroll
    for (int it = 0; it < 4; ++it) {
        int p = tid + it * 256;          // 0..1023
        int e = p >> 4, hh = p & 15;
        const float* qn = q + sDst[e] * 128 + hh * 8;
        float4 q0 = *(const float4*)(qn);
        float4 q1 = *(const float4*)(qn + 4);
        short8 kk = *(const short8*)(&sR[16384 + e * 128 + ((hh ^ (e & 7)) << 3)]);
        float dot = q0.x * bf2f((unsigned short)kk[0]) + q0.y * bf2f((unsigned short)kk[1])
                  + q0.z * bf2f((unsigned short)kk[2]) + q0.w * bf2f((unsigned short)kk[3])
                  + q1.x * bf2f((unsigned short)kk[4]) + q1.y * bf2f((unsigned short)kk[5])
                  + q1.z * bf2f((unsigned short)kk[6]) + q1.w * bf2f((unsigned short)kk[7]);
        logits[(e0 + e) * 16 + hh] = dot * 0.35355339059327373f;
    }
}

// ---------------------- scatter softmax: pass 1 (max) ----------------------
__global__ void k_segmax(const int* __restrict__ ei, const float* __restrict__ logits,
                         unsigned* __restrict__ segmax) {
    int gid = blockIdx.x * 256 + threadIdx.x;
    int e = gid >> 4, hh = gid & 15;
    int d = ei[EE + e];
    atomicMax(&segmax[d * 16 + hh], enc_f32(logits[gid]));
}

// ---------------------- pass 2: exp + denom ----------------------
__global__ void k_exp(const int* __restrict__ ei, float* __restrict__ logits,
                      const unsigned* __restrict__ segmax, float* __restrict__ denom) {
    int gid = blockIdx.x * 256 + threadIdx.x;
    int e = gid >> 4, hh = gid & 15;
    int d = ei[EE + e];
    float m = dec_f32(segmax[d * 16 + hh]);
    float ex = __expf(logits[gid] - m);
    logits[gid] = ex;
    atomicAdd(&denom[d * 16 + hh], ex);
}

// ---------------------- pass 3: scatter to out ----------------------
__global__ void k_scatter(const int* __restrict__ ei, const float* __restrict__ exs,
                          const float* __restrict__ denom, const float* __restrict__ vout,
                          const float* __restrict__ relx, float* __restrict__ out) {
    int e = blockIdx.x * 256 + threadIdx.x;
    int d = ei[EE + e];
    const float* ex = exs + e * 16;
    const float* dn = denom + d * 16;
    const float* vv = vout + e * 16;
    float s = 0.f;
    #pragma unroll
    for (int hh = 0; hh < 16; ++hh) s += ex[hh] / dn[hh] * vv[hh];
    s *= (1.0f / 16.0f);
    atomicAdd(&out[d * 3 + 0], s * relx[e * 3 + 0]);
    atomicAdd(&out[d * 3 + 1], s * relx[e * 3 + 1]);
    atomicAdd(&out[d * 3 + 2], s * relx[e * 3 + 2]);
}

extern "C" void kernel_launch(void* const* d_in, const int* in_sizes, int n_in,
                              void* d_out, int out_size, void* d_ws, size_t ws_size,
                              hipStream_t stream) {
    const float* x   = (const float*)d_in[0];
    const float* h   = (const float*)d_in[1];
    const float* ea  = (const float*)d_in[2];
    const int*   ei  = (const int*)d_in[4];
    const float* kW1 = (const float*)d_in[5];
    const float* kb1 = (const float*)d_in[6];
    const float* kg  = (const float*)d_in[7];
    const float* kbt = (const float*)d_in[8];
    const float* kW2 = (const float*)d_in[9];
    const float* kb2 = (const float*)d_in[10];
    const float* vW1 = (const float*)d_in[11];
    const float* vb1 = (const float*)d_in[12];
    const float* vg  = (const float*)d_in[13];
    const float* vbt = (const float*)d_in[14];
    const float* vW2 = (const float*)d_in[15];
    const float* vb2 = (const float*)d_in[16];
    const float* qW1 = (const float*)d_in[17];
    const float* qb1 = (const float*)d_in[18];
    const float* qg  = (const float*)d_in[19];
    const float* qbt = (const float*)d_in[20];
    const float* qW2 = (const float*)d_in[21];
    const float* qb2 = (const float*)d_in[22];

    float* ws = (float*)d_ws;
    float*    qbuf   = ws;                           // N*128   = 1,280,000
    float*    logits = ws + 1280000;                 // E*16
    float*    vbuf   = ws + 6400000;                 // E*16
    float*    relx   = ws + 11520000;                // E*3
    unsigned* segmax = (unsigned*)(ws + 12480000);   // N*16
    float*    denom  = ws + 12640000;                // N*16
    unsigned short* h_bf  = (unsigned short*)(ws + 12800000);  // N*128 halves
    unsigned short* Wt1   = (unsigned short*)(ws + 13440000);  // 256*352 halves
    unsigned short* kW2t  = (unsigned short*)(ws + 13485056);  // 128*128 halves
    unsigned short* vW2t  = (unsigned short*)(ws + 13493248);  // 16*128 halves
    float* out = (float*)d_out;

    hipLaunchKernelGGL(k_init, dim3(625), dim3(256), 0, stream, segmax, denom, out);
    hipLaunchKernelGGL(k_prep, dim3(5424), dim3(256), 0, stream,
                       h, kW1, vW1, kW2, vW2, h_bf, Wt1, kW2t, vW2t);
    hipLaunchKernelGGL(k_qmlp, dim3(313), dim3(256), 0, stream,
                       h, qW1, qb1, qg, qbt, qW2, qb2, qbuf);
    hipLaunchKernelGGL(k_edge, dim3(5000), dim3(256), 0, stream,
                       x, h_bf, ea, ei, Wt1,
                       kb1, vb1, kg, kbt, vg, vbt,
                       kW2t, kb2, vW2t, vb2,
                       qbuf, logits, vbuf, relx);
    hipLaunchKernelGGL(k_segmax, dim3(20000), dim3(256), 0, stream, ei, logits, segmax);
    hipLaunchKernelGGL(k_exp, dim3(20000), dim3(256), 0, stream, ei, logits, segmax, denom);
    hipLaunchKernelGGL(k_scatter, dim3(1250), dim3(256), 0, stream,
                       ei, logits, denom, vbuf, relx, out);
}